// Round 2
// baseline (588.921 us; speedup 1.0000x reference)
//
#include <hip/hip_runtime.h>
#include <math.h>

#define NN 16384
#define KK 16
#define RPW 4   // rows per wave

__device__ __forceinline__ bool lexless(float da, int ia, float db, int ib) {
    return (da < db) || ((da == db) && (ia < ib));
}

// Pack nodes (N,3) into SoA float4 {x, y, z, sq} — sq with the reference's
// un-contracted arithmetic ((x*x + y*y) + z*z), bit-identical to round 1.
__global__ void prep_kernel(const float* __restrict__ nodes,
                            float4* __restrict__ pts) {
#pragma clang fp contract(off)
    const int i = blockIdx.x * blockDim.x + threadIdx.x;
    if (i < NN) {
        const float x = nodes[3 * i + 0];
        const float y = nodes[3 * i + 1];
        const float z = nodes[3 * i + 2];
        const float sq = (x * x + y * y) + z * z;
        pts[i] = make_float4(x, y, z, sq);
    }
}

// One wave handles RPW=4 rows. Per-row top-17 list distributed across lanes
// 0..16, sorted lex-ascending by (dist, idx); identical insert machinery to
// the verified round-1 kernel, replicated with static indices.
template <int USE_PTS>
__global__ void knn_adj_kernel(const float4* __restrict__ pts,
                               const float* __restrict__ nodes,
                               float* __restrict__ out) {
#pragma clang fp contract(off)
    const int lane = threadIdx.x & 63;
    const int wave = threadIdx.x >> 6;
    const int rowBase = (blockIdx.x * 4 + wave) * RPW;

    float xi[RPW], yi[RPW], zi[RPW], sqi[RPW];
#pragma unroll
    for (int r = 0; r < RPW; ++r) {
        const int row = rowBase + r;
        if (USE_PTS) {
            const float4 p = pts[row];
            xi[r] = p.x; yi[r] = p.y; zi[r] = p.z; sqi[r] = p.w;
        } else {
            xi[r] = nodes[3 * row + 0];
            yi[r] = nodes[3 * row + 1];
            zi[r] = nodes[3 * row + 2];
            sqi[r] = (xi[r] * xi[r] + yi[r] * yi[r]) + zi[r] * zi[r];
        }
    }

    float ld[RPW]; int li[RPW];          // my list entry (lanes 0..16)
    float td[RPW]; int ti[RPW];          // lane-16 (worst kept) broadcast
    float td2u[RPW];                     // conservative d2 screen
#pragma unroll
    for (int r = 0; r < RPW; ++r) {
        ld[r] = INFINITY; li[r] = 0x7fffffff;
        td[r] = INFINITY; ti[r] = 0x7fffffff;
        td2u[r] = INFINITY;
    }

    for (int t = 0; t < NN / 64; ++t) {
        const int j = t * 64 + lane;
        float qx, qy, qz, qw;
        if (USE_PTS) {
            const float4 q = pts[j];
            qx = q.x; qy = q.y; qz = q.z; qw = q.w;
        } else {
            qx = nodes[3 * j + 0];
            qy = nodes[3 * j + 1];
            qz = nodes[3 * j + 2];
            qw = (qx * qx + qy * qy) + qz * qz;
        }

        float d2[RPW]; bool rough[RPW];
        bool anyr = false;
#pragma unroll
        for (int r = 0; r < RPW; ++r) {
            // Reference matmul fma chain: fma(z,z', fma(y,y', x*x')).
            const float dot = fmaf(zi[r], qz, fmaf(yi[r], qy, xi[r] * qx));
            d2[r] = (sqi[r] + qw) - 2.0f * dot;   // contract off: mul+sub as ref
            rough[r] = (d2[r] <= td2u[r]);
            anyr = anyr | rough[r];
        }
        if (__any(anyr)) {
#pragma unroll
            for (int r = 0; r < RPW; ++r) {
                if (!__any(rough[r])) continue;
                float dist = INFINITY;
                if (rough[r]) dist = sqrtf(fmaxf(d2[r], 0.0f));  // IEEE, as ref
                bool done = false;
                while (true) {
                    const bool pass = (!done) && rough[r] &&
                                      lexless(dist, j, td[r], ti[r]);
                    const unsigned long long m = __ballot(pass);
                    if (m == 0ull) break;
                    const int src = __ffsll(m) - 1;
                    const float dc = __shfl(dist, src);
                    const int   ic = __shfl(j, src);
                    if (lane == src) done = true;
                    // Insert (dc,ic) into distributed sorted list.
                    const bool gt = lexless(dc, ic, ld[r], li[r]);
                    const unsigned long long gm = __ballot(gt);
                    const int p = __ffsll(gm) - 1;
                    const float pd = __shfl_up(ld[r], 1);
                    const int   pi = __shfl_up(li[r], 1);
                    if (gt) {
                        if (lane == p) { ld[r] = dc; li[r] = ic; }
                        else           { ld[r] = pd; li[r] = pi; }
                    }
                    td[r]  = __shfl(ld[r], 16);
                    ti[r]  = __shfl(li[r], 16);
                    td2u[r] = td[r] * td[r] * 1.000001f;
                }
            }
        }
    }

    // ---- Write phase: zero 4 rows coalesced, drain, owner-lane 1.0s ----
    const float4 z4 = make_float4(0.f, 0.f, 0.f, 0.f);
#pragma unroll
    for (int r = 0; r < RPW; ++r) {
        float* orow = out + (size_t)(rowBase + r) * NN;
#pragma unroll 4
        for (int u = 0; u < NN / 256; ++u)
            *reinterpret_cast<float4*>(orow + u * 256 + lane * 4) = z4;
    }
    asm volatile("s_waitcnt vmcnt(0)" ::: "memory");
#pragma unroll
    for (int r = 0; r < RPW; ++r) {
        float* orow = out + (size_t)(rowBase + r) * NN;
#pragma unroll
        for (int m = 0; m < KK; ++m) {
            const int c = __shfl(li[r], m + 1);   // lanes 1..16: the K neighbors
            if (((c >> 2) & 63) == lane) orow[c] = 1.0f;  // same lane as zeroing
        }
    }
}

extern "C" void kernel_launch(void* const* d_in, const int* in_sizes, int n_in,
                              void* d_out, int out_size, void* d_ws, size_t ws_size,
                              hipStream_t stream) {
    const float* nodes = (const float*)d_in[0];
    float* out = (float*)d_out;
    (void)in_sizes; (void)n_in; (void)out_size;

    const dim3 block(256);
    const dim3 grid(NN / (4 * RPW));   // 4 waves/block × 4 rows/wave

    if (ws_size >= (size_t)NN * sizeof(float4)) {
        float4* pts = (float4*)d_ws;
        hipLaunchKernelGGL(prep_kernel, dim3(NN / 256), block, 0, stream,
                           nodes, pts);
        hipLaunchKernelGGL((knn_adj_kernel<1>), grid, block, 0, stream,
                           pts, nodes, out);
    } else {
        hipLaunchKernelGGL((knn_adj_kernel<0>), grid, block, 0, stream,
                           (const float4*)nullptr, nodes, out);
    }
}

// Round 3
// 367.775 us; speedup vs baseline: 1.6013x; 1.6013x over previous
//
#include <hip/hip_runtime.h>
#include <math.h>

#define NN 16384
#define KK 16

__device__ __forceinline__ bool lexless(float da, int ia, float db, int ib) {
    return (da < db) || ((da == db) && (ia < ib));
}

// Pack nodes (N,3) into SoA float4 {x, y, z, sq}; sq with the reference's
// un-contracted arithmetic ((x*x + y*y) + z*z).
__global__ void prep_kernel(const float* __restrict__ nodes,
                            float4* __restrict__ pts) {
#pragma clang fp contract(off)
    const int i = blockIdx.x * blockDim.x + threadIdx.x;
    if (i < NN) {
        const float x = nodes[3 * i + 0];
        const float y = nodes[3 * i + 1];
        const float z = nodes[3 * i + 2];
        pts[i] = make_float4(x, y, z, (x * x + y * y) + z * z);
    }
}

// Verified distributed-sorted-list insert (identical machinery to rounds 1-2).
__device__ __forceinline__ void insert_tile(bool rough, float d2, int j,
                                            float& ld, int& li,
                                            float& td, int& ti, float& td2u,
                                            int lane) {
#pragma clang fp contract(off)
    if (!__any(rough)) return;
    float dist = INFINITY;
    if (rough) dist = sqrtf(fmaxf(d2, 0.0f));   // IEEE sqrt, matches reference
    bool done = false;
    while (true) {
        const bool pass = (!done) && rough && lexless(dist, j, td, ti);
        const unsigned long long m = __ballot(pass);
        if (m == 0ull) break;
        const int src = __ffsll(m) - 1;
        const float dc = __shfl(dist, src);
        const int   ic = __shfl(j, src);
        if (lane == src) done = true;
        const bool gt = lexless(dc, ic, ld, li);
        const unsigned long long gm = __ballot(gt);
        const int p = __ffsll(gm) - 1;
        const float pd = __shfl_up(ld, 1);
        const int   pi = __shfl_up(li, 1);
        if (gt) {
            if (lane == p) { ld = dc; li = ic; }
            else           { ld = pd; li = pi; }
        }
        td = __shfl(ld, 16);
        ti = __shfl(li, 16);
        td2u = td * td * 1.000001f;   // conservative d2-domain screen bound
    }
}

// One wave per row; 128 candidates per iteration (2 float4 tiles), software-
// pipelined loads; the row's zero-fill interleaved into the scan so the
// 1 GiB store stream hides under compute.
__global__ __launch_bounds__(256) void knn_adj_kernel(
        const float4* __restrict__ pts, float* __restrict__ out) {
#pragma clang fp contract(off)
    const int lane = threadIdx.x & 63;
    const int wave = threadIdx.x >> 6;
    const int row  = blockIdx.x * 4 + wave;

    const float4 p = pts[row];
    const float xi = p.x, yi = p.y, zi = p.z, sqi = p.w;

    float ld = INFINITY; int li = 0x7fffffff;   // my list slot (lanes 0..16)
    float td = INFINITY; int ti = 0x7fffffff;   // lane-16 (worst kept)
    float td2u = INFINITY;

    float* orow = out + (size_t)row * NN;
    const float4 z4 = make_float4(0.f, 0.f, 0.f, 0.f);

    float4 q0 = pts[lane];
    float4 q1 = pts[64 + lane];

    for (int t = 0; t < NN / 128; ++t) {
        const int base = t * 128;
        // Prefetch next iteration's tiles (clamped re-read on the last iter).
        const int nxt = (t + 1 < NN / 128) ? (t + 1) * 128 : base;
        const float4 n0 = pts[nxt + lane];
        const float4 n1 = pts[nxt + 64 + lane];
        // Interleaved zero-fill: 64 coalesced 1 KB bursts over 128 iters.
        if (t < NN / 256)
            *reinterpret_cast<float4*>(orow + t * 256 + lane * 4) = z4;

        // Reference arithmetic: fma-chain dot, un-contracted d2.
        const float dot0 = fmaf(zi, q0.z, fmaf(yi, q0.y, xi * q0.x));
        const float d20  = (sqi + q0.w) - 2.0f * dot0;
        const float dot1 = fmaf(zi, q1.z, fmaf(yi, q1.y, xi * q1.x));
        const float d21  = (sqi + q1.w) - 2.0f * dot1;
        const bool r0 = (d20 <= td2u);
        const bool r1 = (d21 <= td2u);

        insert_tile(r0, d20, base + lane,      ld, li, td, ti, td2u, lane);
        insert_tile(r1, d21, base + 64 + lane, ld, li, td, ti, td2u, lane);

        q0 = n0; q1 = n1;
    }

    // Drain zero stores, then owner-lane 1.0 overwrites (same-lane ordering).
    asm volatile("s_waitcnt vmcnt(0)" ::: "memory");
#pragma unroll
    for (int m = 0; m < KK; ++m) {
        const int c = __shfl(li, m + 1);        // lanes 1..16 = the K neighbors
        if (((c >> 2) & 63) == lane) orow[c] = 1.0f;
    }
}

extern "C" void kernel_launch(void* const* d_in, const int* in_sizes, int n_in,
                              void* d_out, int out_size, void* d_ws, size_t ws_size,
                              hipStream_t stream) {
    const float* nodes = (const float*)d_in[0];
    float* out = (float*)d_out;
    (void)in_sizes; (void)n_in; (void)out_size; (void)ws_size;

    float4* pts = (float4*)d_ws;    // 256 KB, ws is preallocated scratch
    hipLaunchKernelGGL(prep_kernel, dim3(NN / 256), dim3(256), 0, stream,
                       nodes, pts);
    hipLaunchKernelGGL(knn_adj_kernel, dim3(NN / 4), dim3(256), 0, stream,
                       pts, out);
}